// Round 29
// baseline (140.427 us; speedup 1.0000x reference)
//
#include <hip/hip_runtime.h>

typedef unsigned int u32;
typedef unsigned short u16;
typedef __attribute__((ext_vector_type(4))) float f32x4;
typedef __attribute__((ext_vector_type(8))) short s16x8;

#define XS_F  ((float)(100.0/448.0))
#define WS_F  ((float)(1.6/448.0))
#define OSC_F ((float)((100.0/448.0)*(1.6/448.0)))

// RNE onto fp8-e4m3 grid (clip 448, min exp -6): bf16 bit pattern
__device__ __forceinline__ u32 qpat(float y){
  float a = fminf(fabsf(y), 448.0f);
  u32 eb = __float_as_uint(a) & 0x7f800000u;
  if (eb < (121u << 23)) eb = (121u << 23);
  float C = __uint_as_float(eb + (20u << 23));
  float q = (a + C) - C;
  return (__float_as_uint(q) >> 16) | ((__float_as_uint(y) >> 16) & 0x8000u);
}

__device__ __forceinline__ uint4 qpack(const float4 a, const float4 b){
  uint4 r;
  r.x = qpat(a.x/XS_F) | (qpat(a.y/XS_F) << 16);
  r.y = qpat(a.z/XS_F) | (qpat(a.w/XS_F) << 16);
  r.z = qpat(b.x/XS_F) | (qpat(b.y/XS_F) << 16);
  r.w = qpat(b.z/XS_F) | (qpat(b.w/XS_F) << 16);
  return r;
}

// Producer (identity layout, device-verified r28): wq[c][k] = q(w[k*256+c]/WS).
__global__ __launch_bounds__(256) void wq_r29(const float* __restrict__ w,
                                              u16* __restrict__ wq)
{
  const int t = blockIdx.x * 256 + threadIdx.x;
  const int c = t >> 7;
  const int k = (t & 127) << 1;
  const u32 p0 = qpat(w[(k  )*256 + c] / WS_F);
  const u32 p1 = qpat(w[(k+1)*256 + c] / WS_F);
  *reinterpret_cast<u32*>(wq + c*256 + k) = p0 | (p1 << 16);
}

// GEMM. Data mapping: identity (r28 on-device 3-equation check passed).
// MFMA placement (r15/r16 HW-verified): mfma(x_frag, w_frag) -> reg j = x row,
// lane&15 = w col. OUTPUT IS FLOAT32 (r28 decode: d_out = f32[67108864];
// comparator reads f32[j] vs np-f32 ref[j]; the bf16 assumption was the
// 28-round bug). Full N=262144 rows -> 1024 blocks x 512 threads.
template<bool USE_WS>
__global__ __launch_bounds__(512) void gemm_r29(
    const float* __restrict__ x, const u16* __restrict__ wq,
    const float* __restrict__ wraw, float* __restrict__ out)
{
  __shared__ __align__(16) unsigned char sx[2][16384];  // 2 x (32 rows x 256 k) bf16

  const int tid  = threadIdx.x;
  const int lane = tid & 63;
  const int wid  = tid >> 6;
  const int l15  = lane & 15;
  const int lg   = lane >> 4;
  const int Rblk = blockIdx.x << 8;   // 256 rows per block

  s16x8 wfrag[2][8];
  #pragma unroll
  for (int ct = 0; ct < 2; ++ct){
    const int col = wid*32 + ct*16 + l15;
    if (USE_WS){
      #pragma unroll
      for (int kc = 0; kc < 8; ++kc)
        wfrag[ct][kc] = *reinterpret_cast<const s16x8*>(wq + col*256 + kc*32 + lg*8);
    } else {
      #pragma unroll
      for (int kc = 0; kc < 8; ++kc){
        s16x8 f;
        #pragma unroll
        for (int j = 0; j < 8; ++j)
          f[j] = (short)qpat(wraw[(kc*32 + lg*8 + j)*256 + col] / WS_F);
        wfrag[ct][kc] = f;
      }
    }
  }

  const int srow = tid >> 4;
  const int seg  = tid & 15;
  const int swzW = (srow & 7) << 4;
  const int ldsA = srow*512 + ((seg*32     ) ^ swzW);
  const int ldsB = srow*512 + ((seg*32 + 16) ^ swzW);
  const float* xg = x + (Rblk + srow)*256 + seg*16;

  {
    const float4 g0 = *reinterpret_cast<const float4*>(xg);
    const float4 g1 = *reinterpret_cast<const float4*>(xg + 4);
    const float4 g2 = *reinterpret_cast<const float4*>(xg + 8);
    const float4 g3 = *reinterpret_cast<const float4*>(xg + 12);
    *reinterpret_cast<uint4*>(&sx[0][ldsA]) = qpack(g0, g1);
    *reinterpret_cast<uint4*>(&sx[0][ldsB]) = qpack(g2, g3);
  }
  __syncthreads();

  for (int t = 0; t < 8; ++t){
    const int cur   = t & 1;
    const bool more = (t < 7);
    float4 n0, n1, n2, n3;
    if (more){
      const float* nxtp = xg + (t+1)*8192;
      n0 = *reinterpret_cast<const float4*>(nxtp);
      n1 = *reinterpret_cast<const float4*>(nxtp + 4);
      n2 = *reinterpret_cast<const float4*>(nxtp + 8);
      n3 = *reinterpret_cast<const float4*>(nxtp + 12);
    }

    f32x4 acc[2][2];
    #pragma unroll
    for (int rt = 0; rt < 2; ++rt)
      #pragma unroll
      for (int ct = 0; ct < 2; ++ct)
        acc[rt][ct] = (f32x4){0.f, 0.f, 0.f, 0.f};

    #pragma unroll
    for (int kc = 0; kc < 8; ++kc){
      s16x8 bfr[2];
      #pragma unroll
      for (int rt = 0; rt < 2; ++rt){
        const int row = rt*16 + l15;
        const int off = row*512 + (((kc*64) + lg*16) ^ ((row & 7) << 4));
        bfr[rt] = *reinterpret_cast<const s16x8*>(&sx[cur][off]);
      }
      #pragma unroll
      for (int rt = 0; rt < 2; ++rt)
        #pragma unroll
        for (int ct = 0; ct < 2; ++ct)
          acc[rt][ct] = __builtin_amdgcn_mfma_f32_16x16x32_bf16(
              bfr[rt], wfrag[ct][kc], acc[rt][ct], 0, 0, 0);
    }

    // f32 epilogue: reg j -> x row, l15 -> w col (16 lanes = 16 consecutive cols)
    #pragma unroll
    for (int rt = 0; rt < 2; ++rt){
      const int rbase = Rblk + t*32 + rt*16 + lg*4;
      #pragma unroll
      for (int ct = 0; ct < 2; ++ct){
        const int wcol = wid*32 + ct*16 + l15;
        #pragma unroll
        for (int j = 0; j < 4; ++j)
          out[(rbase + j)*256 + wcol] = acc[rt][ct][j] * OSC_F;
      }
    }

    if (more){
      const int nxt = cur ^ 1;
      *reinterpret_cast<uint4*>(&sx[nxt][ldsA]) = qpack(n0, n1);
      *reinterpret_cast<uint4*>(&sx[nxt][ldsB]) = qpack(n2, n3);
    }
    __syncthreads();
  }
}

extern "C" void kernel_launch(void* const* d_in, const int* in_sizes, int n_in,
                              void* d_out, int out_size, void* d_ws, size_t ws_size,
                              hipStream_t stream)
{
  // Inputs f32, identity layout (r11 + r28 on-device equation check).
  // OUTPUT f32[out_size] — the harness's expected dtype (r28 decode).
  const int ix = (in_sizes[0] >= in_sizes[1]) ? 0 : 1;
  const int iw = 1 - ix;
  const float* x = (const float*)d_in[ix];
  const float* w = (const float*)d_in[iw];
  float*     out = (float*)d_out;
  const int rows   = in_sizes[ix] >> 8;   // 262144
  const int blocks = rows >> 8;           // 1024 (256 rows per block)

  if (ws_size >= (size_t)131072){
    wq_r29<<<dim3(128), dim3(256), 0, stream>>>(w, (u16*)d_ws);
    gemm_r29<true><<<dim3(blocks), dim3(512), 0, stream>>>(
        x, (const u16*)d_ws, w, out);
  } else {
    gemm_r29<false><<<dim3(blocks), dim3(512), 0, stream>>>(
        x, nullptr, w, out);
  }
}

// Round 30
// 124.455 us; speedup vs baseline: 1.1283x; 1.1283x over previous
//
#include <hip/hip_runtime.h>

typedef unsigned int u32;
typedef unsigned short u16;
typedef __attribute__((ext_vector_type(4))) float f32x4;
typedef __attribute__((ext_vector_type(8))) short s16x8;

#define XS_F  ((float)(100.0/448.0))
#define WS_F  ((float)(1.6/448.0))
#define OSC_F ((float)((100.0/448.0)*(1.6/448.0)))

// Correctly-rounded division by a positive constant (Markstein sequence):
// r = RN(1/b) at compile time; q0 = RN(a*r); e = fma(-b,q0,a); q = fma(e,r,q0).
// IEEE-equivalent to a/b in round-to-nearest; 3 VALU ops vs ~10 for v_div_*.
__device__ __forceinline__ float div_xs(float a){
  const float r = 1.0f / XS_F;
  float q0 = a * r;
  float e  = __builtin_fmaf(-XS_F, q0, a);
  return __builtin_fmaf(e, r, q0);
}
__device__ __forceinline__ float div_ws(float a){
  const float r = 1.0f / WS_F;
  float q0 = a * r;
  float e  = __builtin_fmaf(-WS_F, q0, a);
  return __builtin_fmaf(e, r, q0);
}

// RNE onto fp8-e4m3 grid (clip 448, min exp -6): bf16 bit pattern
__device__ __forceinline__ u32 qpat(float y){
  float a = fminf(fabsf(y), 448.0f);
  u32 eb = __float_as_uint(a) & 0x7f800000u;
  if (eb < (121u << 23)) eb = (121u << 23);
  float C = __uint_as_float(eb + (20u << 23));
  float q = (a + C) - C;
  return (__float_as_uint(q) >> 16) | ((__float_as_uint(y) >> 16) & 0x8000u);
}

__device__ __forceinline__ uint4 qpack(const float4 a, const float4 b){
  uint4 r;
  r.x = qpat(div_xs(a.x)) | (qpat(div_xs(a.y)) << 16);
  r.y = qpat(div_xs(a.z)) | (qpat(div_xs(a.w)) << 16);
  r.z = qpat(div_xs(b.x)) | (qpat(div_xs(b.y)) << 16);
  r.w = qpat(div_xs(b.z)) | (qpat(div_xs(b.w)) << 16);
  return r;
}

// Producer: wq[c][k] = q(w[k*256+c]/WS), 128 KB bf16-patterns.
__global__ __launch_bounds__(256) void wq_r30(const float* __restrict__ w,
                                              u16* __restrict__ wq)
{
  const int t = blockIdx.x * 256 + threadIdx.x;
  const int c = t >> 7;
  const int k = (t & 127) << 1;
  const u32 p0 = qpat(div_ws(w[(k  )*256 + c]));
  const u32 p1 = qpat(div_ws(w[(k+1)*256 + c]));
  *reinterpret_cast<u32*>(wq + c*256 + k) = p0 | (p1 << 16);
}

// GEMM (identity data, f32 in/out — r28/r29 verified).
// r30: operands SWAPPED to mfma(wfrag, bfr): D reg-quad = 4 consecutive w cols,
// D lane&15 = x row (transpose of the r15/r16-verified map; element values
// bit-identical) -> epilogue is 4x float4 stores per thread per tile.
template<bool USE_WS>
__global__ __launch_bounds__(512) void gemm_r30(
    const float* __restrict__ x, const u16* __restrict__ wq,
    const float* __restrict__ wraw, float* __restrict__ out)
{
  __shared__ __align__(16) unsigned char sx[2][16384];  // 2 x (32 rows x 256 k) bf16

  const int tid  = threadIdx.x;
  const int lane = tid & 63;
  const int wid  = tid >> 6;
  const int l15  = lane & 15;
  const int lg   = lane >> 4;
  const int Rblk = blockIdx.x << 8;   // 256 rows per block

  s16x8 wfrag[2][8];
  #pragma unroll
  for (int ct = 0; ct < 2; ++ct){
    const int col = wid*32 + ct*16 + l15;
    if (USE_WS){
      #pragma unroll
      for (int kc = 0; kc < 8; ++kc)
        wfrag[ct][kc] = *reinterpret_cast<const s16x8*>(wq + col*256 + kc*32 + lg*8);
    } else {
      #pragma unroll
      for (int kc = 0; kc < 8; ++kc){
        s16x8 f;
        #pragma unroll
        for (int j = 0; j < 8; ++j)
          f[j] = (short)qpat(div_ws(wraw[(kc*32 + lg*8 + j)*256 + col]));
        wfrag[ct][kc] = f;
      }
    }
  }

  const int srow = tid >> 4;
  const int seg  = tid & 15;
  const int swzW = (srow & 7) << 4;
  const int ldsA = srow*512 + ((seg*32     ) ^ swzW);
  const int ldsB = srow*512 + ((seg*32 + 16) ^ swzW);
  const float* xg = x + (Rblk + srow)*256 + seg*16;

  {
    const float4 g0 = *reinterpret_cast<const float4*>(xg);
    const float4 g1 = *reinterpret_cast<const float4*>(xg + 4);
    const float4 g2 = *reinterpret_cast<const float4*>(xg + 8);
    const float4 g3 = *reinterpret_cast<const float4*>(xg + 12);
    *reinterpret_cast<uint4*>(&sx[0][ldsA]) = qpack(g0, g1);
    *reinterpret_cast<uint4*>(&sx[0][ldsB]) = qpack(g2, g3);
  }
  __syncthreads();

  for (int t = 0; t < 8; ++t){
    const int cur   = t & 1;
    const bool more = (t < 7);
    float4 n0, n1, n2, n3;
    if (more){
      const float* nxtp = xg + (t+1)*8192;
      n0 = *reinterpret_cast<const float4*>(nxtp);
      n1 = *reinterpret_cast<const float4*>(nxtp + 4);
      n2 = *reinterpret_cast<const float4*>(nxtp + 8);
      n3 = *reinterpret_cast<const float4*>(nxtp + 12);
    }

    f32x4 acc[2][2];
    #pragma unroll
    for (int rt = 0; rt < 2; ++rt)
      #pragma unroll
      for (int ct = 0; ct < 2; ++ct)
        acc[rt][ct] = (f32x4){0.f, 0.f, 0.f, 0.f};

    #pragma unroll
    for (int kc = 0; kc < 8; ++kc){
      s16x8 bfr[2];
      #pragma unroll
      for (int rt = 0; rt < 2; ++rt){
        const int row = rt*16 + l15;
        const int off = row*512 + (((kc*64) + lg*16) ^ ((row & 7) << 4));
        bfr[rt] = *reinterpret_cast<const s16x8*>(&sx[cur][off]);
      }
      #pragma unroll
      for (int rt = 0; rt < 2; ++rt)
        #pragma unroll
        for (int ct = 0; ct < 2; ++ct)
          acc[rt][ct] = __builtin_amdgcn_mfma_f32_16x16x32_bf16(
              wfrag[ct][kc], bfr[rt], acc[rt][ct], 0, 0, 0);   // swapped
    }

    // epilogue: lane l15 = x row; reg quad = 4 consecutive w cols -> float4
    #pragma unroll
    for (int rt = 0; rt < 2; ++rt){
      const int xrow = Rblk + t*32 + rt*16 + l15;
      #pragma unroll
      for (int ct = 0; ct < 2; ++ct){
        const int wcol = wid*32 + ct*16 + lg*4;
        float4 s;
        s.x = acc[rt][ct][0] * OSC_F;
        s.y = acc[rt][ct][1] * OSC_F;
        s.z = acc[rt][ct][2] * OSC_F;
        s.w = acc[rt][ct][3] * OSC_F;
        *reinterpret_cast<float4*>(out + xrow*256 + wcol) = s;
      }
    }

    if (more){
      const int nxt = cur ^ 1;
      *reinterpret_cast<uint4*>(&sx[nxt][ldsA]) = qpack(n0, n1);
      *reinterpret_cast<uint4*>(&sx[nxt][ldsB]) = qpack(n2, n3);
    }
    __syncthreads();
  }
}

extern "C" void kernel_launch(void* const* d_in, const int* in_sizes, int n_in,
                              void* d_out, int out_size, void* d_ws, size_t ws_size,
                              hipStream_t stream)
{
  const int ix = (in_sizes[0] >= in_sizes[1]) ? 0 : 1;
  const int iw = 1 - ix;
  const float* x = (const float*)d_in[ix];
  const float* w = (const float*)d_in[iw];
  float*     out = (float*)d_out;
  const int rows   = in_sizes[ix] >> 8;   // 262144
  const int blocks = rows >> 8;           // 1024

  if (ws_size >= (size_t)131072){
    wq_r30<<<dim3(128), dim3(256), 0, stream>>>(w, (u16*)d_ws);
    gemm_r30<true><<<dim3(blocks), dim3(512), 0, stream>>>(
        x, (const u16*)d_ws, w, out);
  } else {
    gemm_r30<false><<<dim3(blocks), dim3(512), 0, stream>>>(
        x, nullptr, w, out);
  }
}